// Round 3
// baseline (613.910 us; speedup 1.0000x reference)
//
#include <hip/hip_runtime.h>
#include <hip/hip_bf16.h>

#define B_ 8
#define E_ 2048
#define N_ 2048
#define F_ 128

#define BM 16      // hyperedge rows per block
#define BK 64      // K chunk
#define AP 72      // A tile LDS pitch (bf16 elems), padded
#define BP 72      // B tile LDS pitch
#define MP 136     // msg LDS pitch

using bf16x8 = __bf16 __attribute__((ext_vector_type(8)));
using fx4    = float __attribute__((ext_vector_type(4)));

// ---------------- prep: node [B][N][F] f32 -> nodeT [B][F][N] bf16 ----------------
// No LDS. lane<->f so the strided loads coalesce across the wave; each thread
// packs 16 consecutive n at fixed f and writes 32 B contiguous along n.
__global__ __launch_bounds__(256) void prep_node(const float* __restrict__ node,
                                                 __bf16* __restrict__ nodeT) {
    const int bid = blockIdx.x;          // 512 blocks
    const int b   = bid & 7;
    const int n0  = (bid >> 3) * 32;
    const int t   = threadIdx.x;
    const int f   = t & 127;
    const int nb  = n0 + (t >> 7) * 16;

    const float* src = node + ((size_t)b * N_ + nb) * F_ + f;
    __bf16 h[16];
#pragma unroll
    for (int i = 0; i < 16; ++i)
        h[i] = (__bf16)src[(size_t)i * F_];

    __bf16* dst = nodeT + ((size_t)b * F_ + f) * N_ + nb;
    *(uint4*)&dst[0] = *(const uint4*)&h[0];
    *(uint4*)&dst[8] = *(const uint4*)&h[8];
}

// ---------------- prep: W f32 -> bf16 ----------------
__global__ __launch_bounds__(256) void prep_w(const float* __restrict__ W,
                                              __bf16* __restrict__ Wb) {
    int idx = blockIdx.x * 256 + threadIdx.x;   // 0..4095
    float4 v = *(const float4*)&W[idx * 4];
    __bf16 o[4] = {(__bf16)v.x, (__bf16)v.y, (__bf16)v.z, (__bf16)v.w};
    *(uint2*)&Wb[idx * 4] = *(const uint2*)o;
}

// ---------------- main fused kernel ----------------
__global__ __launch_bounds__(256, 4) void v2h_main(const float* __restrict__ adj,
                                                   const __bf16* __restrict__ nodeT,
                                                   const __bf16* __restrict__ Wb,
                                                   const float* __restrict__ bias,
                                                   float* __restrict__ out) {
    __shared__ __align__(16) __bf16 smemAB[BM * AP + F_ * BP];   // 10368 elems ~20.7 KB
    __shared__ float normS[BM];

    __bf16* As = smemAB;                 // [BM][AP]
    __bf16* Bs = smemAB + BM * AP;       // [F_][BP]  (f-major, k-contiguous)
    __bf16* Ms = smemAB;                 // [BM][MP]  (epilogue reuse)

    const int t    = threadIdx.x;
    const int bid  = blockIdx.x;
    const int b    = bid & 7;            // batch -> XCD locality for nodeT
    const int e0   = (bid >> 3) * BM;
    const int wf   = t >> 6;             // wave id = f-group (32 cols each)
    const int lane = t & 63;
    const int l15  = lane & 15;
    const int quad = lane >> 4;

    fx4 acc[2] = {};
    float cnt = 0.f;                     // per-thread partial -1 count

    const int ar0 = t >> 4;              // A row: 0..15
    const int ac  = (t & 15) * 4;        // A col base
    const float*  adjR = adj + ((size_t)b * E_ + e0 + ar0) * N_;
    const __bf16* nTB  = nodeT + (size_t)b * F_ * N_;

    // ---- prologue: load tile k=0 into registers ----
    float4 aR = *(const float4*)(adjR + ac);
    uint4 bR[4];
#pragma unroll
    for (int p = 0; p < 4; ++p) {
        int idx = t + 256 * p;           // 0..1023
        int f   = idx >> 3;              // 0..127
        int k8  = (idx & 7) * 8;         // 0..56
        bR[p] = *(const uint4*)&nTB[(size_t)f * N_ + k8];
    }

    for (int k0 = 0; k0 < N_; k0 += BK) {
        // ---- prefetch next tile (wrap on last iter; harmless) ----
        const int kn = (k0 + BK) & (N_ - 1);
        float4 aN = *(const float4*)(adjR + kn + ac);
        uint4 bN[4];
#pragma unroll
        for (int p = 0; p < 4; ++p) {
            int idx = t + 256 * p;
            int f   = idx >> 3;
            int k8  = (idx & 7) * 8;
            bN[p] = *(const uint4*)&nTB[(size_t)f * N_ + kn + k8];
        }

        __syncthreads();   // previous iteration's LDS reads complete

        // mask convert + store A, accumulate norm count (waits only on aR/bR)
        {
            float m0 = (aR.x == -1.f) ? 1.f : 0.f;
            float m1 = (aR.y == -1.f) ? 1.f : 0.f;
            float m2 = (aR.z == -1.f) ? 1.f : 0.f;
            float m3 = (aR.w == -1.f) ? 1.f : 0.f;
            cnt += m0 + m1 + m2 + m3;
            __bf16 pk[4] = {(__bf16)m0, (__bf16)m1, (__bf16)m2, (__bf16)m3};
            *(uint2*)&As[ar0 * AP + ac] = *(const uint2*)pk;
        }
#pragma unroll
        for (int p = 0; p < 4; ++p) {
            int idx = t + 256 * p;
            int f   = idx >> 3;
            int k8  = (idx & 7) * 8;
            *(uint4*)&Bs[f * BP + k8] = bR[p];
        }

        __syncthreads();   // tiles visible

        // MFMA: A[m=lane&15][k=quad*8+j], B[k][n=f-col]
#pragma unroll
        for (int ks = 0; ks < 2; ++ks) {
            bf16x8 af = *(const bf16x8*)&As[l15 * AP + ks * 32 + quad * 8];
#pragma unroll
            for (int ft = 0; ft < 2; ++ft) {
                bf16x8 bf = *(const bf16x8*)&Bs[(wf * 32 + ft * 16 + l15) * BP + ks * 32 + quad * 8];
                acc[ft] = __builtin_amdgcn_mfma_f32_16x16x32_bf16(af, bf, acc[ft], 0, 0, 0);
            }
        }

        aR = aN;
#pragma unroll
        for (int p = 0; p < 4; ++p) bR[p] = bN[p];
    }

    // ---- norm reduction: 16 threads (lane&15) share each row ----
#pragma unroll
    for (int m = 1; m < 16; m <<= 1)
        cnt += __shfl_xor(cnt, m);
    if ((t & 15) == 0)
        normS[ar0] = fmaxf(cnt, 1.f);
    __syncthreads();   // normS ready; all K-loop LDS reads done -> Ms reuse safe

    // ---- scale by 1/norm, write msg (bf16) to LDS in [m][f] layout ----
    const int rbase = quad * 4;
    float rn[4];
#pragma unroll
    for (int r = 0; r < 4; ++r) rn[r] = 1.f / normS[rbase + r];
#pragma unroll
    for (int ft = 0; ft < 2; ++ft) {
        int fcol = wf * 32 + ft * 16 + l15;
#pragma unroll
        for (int r = 0; r < 4; ++r)
            Ms[(rbase + r) * MP + fcol] = (__bf16)(acc[ft][r] * rn[r]);
    }
    __syncthreads();

    // ---- second GEMM: out[m][g] = sum_f msg[m][f] * W[g][f]; W read direct from global ----
    fx4 acc2[2] = {};
#pragma unroll
    for (int ks = 0; ks < 4; ++ks) {
        bf16x8 af = *(const bf16x8*)&Ms[l15 * MP + ks * 32 + quad * 8];
#pragma unroll
        for (int gt = 0; gt < 2; ++gt) {
            int g = wf * 32 + gt * 16 + l15;
            bf16x8 wfr = *(const bf16x8*)&Wb[(size_t)g * F_ + ks * 32 + quad * 8];
            acc2[gt] = __builtin_amdgcn_mfma_f32_16x16x32_bf16(af, wfr, acc2[gt], 0, 0, 0);
        }
    }

    // ---- bias + relu + store ----
#pragma unroll
    for (int gt = 0; gt < 2; ++gt) {
        int g = wf * 32 + gt * 16 + l15;
        float bb = bias[g];
#pragma unroll
        for (int r = 0; r < 4; ++r) {
            int e = e0 + rbase + r;
            float v = acc2[gt][r] + bb;
            out[((size_t)b * E_ + e) * F_ + g] = fmaxf(v, 0.f);
        }
    }
}

extern "C" void kernel_launch(void* const* d_in, const int* in_sizes, int n_in,
                              void* d_out, int out_size, void* d_ws, size_t ws_size,
                              hipStream_t stream) {
    const float* node = (const float*)d_in[0];   // [B,N,F]
    const float* adj  = (const float*)d_in[1];   // [B,E,N]
    const float* W    = (const float*)d_in[2];   // [F,F]
    const float* bias = (const float*)d_in[3];   // [F]
    float* out = (float*)d_out;                  // [B,E,F]

    __bf16* nodeT = (__bf16*)d_ws;                                   // 8 MB region
    __bf16* Wb    = (__bf16*)((char*)d_ws + (size_t)B_ * F_ * N_ * 2);

    prep_node<<<512, 256, 0, stream>>>(node, nodeT);
    prep_w<<<16, 256, 0, stream>>>(W, Wb);
    v2h_main<<<1024, 256, 0, stream>>>(adj, nodeT, Wb, bias, out);
}

// Round 4
// 280.206 us; speedup vs baseline: 2.1909x; 2.1909x over previous
//
#include <hip/hip_runtime.h>
#include <hip/hip_bf16.h>

#define B_ 8
#define E_ 2048
#define N_ 2048
#define F_ 128

#define BM 16      // hyperedge rows per block
#define MP 136     // msg LDS pitch (padded: 272B row stride -> 2-way-free bank pattern)

using bf16x8 = __bf16 __attribute__((ext_vector_type(8)));
using fx4    = float __attribute__((ext_vector_type(4)));

// ---------------- prep: node [B][N][F] f32 -> nodeT [B][F][N] bf16 ----------------
// No LDS. lane<->f so the strided loads coalesce across the wave; each thread
// packs 16 consecutive n at fixed f and writes 32 B contiguous along n.
__global__ __launch_bounds__(256) void prep_node(const float* __restrict__ node,
                                                 __bf16* __restrict__ nodeT) {
    const int bid = blockIdx.x;          // 512 blocks
    const int b   = bid & 7;
    const int n0  = (bid >> 3) * 32;
    const int t   = threadIdx.x;
    const int f   = t & 127;
    const int nb  = n0 + (t >> 7) * 16;

    const float* src = node + ((size_t)b * N_ + nb) * F_ + f;
    __bf16 h[16];
#pragma unroll
    for (int i = 0; i < 16; ++i)
        h[i] = (__bf16)src[(size_t)i * F_];

    __bf16* dst = nodeT + ((size_t)b * F_ + f) * N_ + nb;
    *(uint4*)&dst[0] = *(const uint4*)&h[0];
    *(uint4*)&dst[8] = *(const uint4*)&h[8];
}

// ---------------- prep: W f32 -> bf16 ----------------
__global__ __launch_bounds__(256) void prep_w(const float* __restrict__ W,
                                              __bf16* __restrict__ Wb) {
    int idx = blockIdx.x * 256 + threadIdx.x;   // 0..4095
    float4 v = *(const float4*)&W[idx * 4];
    __bf16 o[4] = {(__bf16)v.x, (__bf16)v.y, (__bf16)v.z, (__bf16)v.w};
    *(uint2*)&Wb[idx * 4] = *(const uint2*)o;
}

// ---------------- main fused kernel: no LDS in the K-loop, no barriers ----------------
__global__ __launch_bounds__(256) void v2h_main(const float* __restrict__ adj,
                                                const __bf16* __restrict__ nodeT,
                                                const __bf16* __restrict__ Wb,
                                                const float* __restrict__ bias,
                                                float* __restrict__ out) {
    __shared__ __align__(16) __bf16 Ms[BM * MP];   // 4352 B: msg layout round-trip

    const int t    = threadIdx.x;
    const int bid  = blockIdx.x;
    const int b    = bid & 7;            // batch -> XCD L2 locality for nodeT[b]
    const int e0   = (bid >> 3) * BM;
    const int wf   = t >> 6;             // wave id = f-group (32 cols each)
    const int lane = t & 63;
    const int l15  = lane & 15;
    const int quad = lane >> 4;

    // A: row e0+l15, k = k0 + quad*8 + j   (each wave redundantly loads A; L1-served)
    const float*  aPtr  = adj + ((size_t)b * E_ + e0 + l15) * N_ + quad * 8;
    // B: f = wf*32 + ft*16 + l15, k = k0 + quad*8 + j
    const __bf16* nTB   = nodeT + (size_t)b * F_ * N_;
    const __bf16* bPtr0 = nTB + (size_t)(wf * 32 + l15) * N_ + quad * 8;
    const __bf16* bPtr1 = bPtr0 + (size_t)16 * N_;

    fx4 acc[2] = {};
    float cnt = 0.f;   // partial -1 count of row l15 over this lane's k slots

#pragma unroll 4
    for (int k0 = 0; k0 < N_; k0 += 32) {
        float4 a0 = *(const float4*)(aPtr + k0);
        float4 a1 = *(const float4*)(aPtr + k0 + 4);
        bf16x8 bf0 = *(const bf16x8*)(bPtr0 + k0);
        bf16x8 bf1 = *(const bf16x8*)(bPtr1 + k0);

        float m0 = (a0.x == -1.f) ? 1.f : 0.f;
        float m1 = (a0.y == -1.f) ? 1.f : 0.f;
        float m2 = (a0.z == -1.f) ? 1.f : 0.f;
        float m3 = (a0.w == -1.f) ? 1.f : 0.f;
        float m4 = (a1.x == -1.f) ? 1.f : 0.f;
        float m5 = (a1.y == -1.f) ? 1.f : 0.f;
        float m6 = (a1.z == -1.f) ? 1.f : 0.f;
        float m7 = (a1.w == -1.f) ? 1.f : 0.f;
        cnt += (m0 + m1) + (m2 + m3) + ((m4 + m5) + (m6 + m7));

        bf16x8 af;
        af[0] = (__bf16)m0; af[1] = (__bf16)m1; af[2] = (__bf16)m2; af[3] = (__bf16)m3;
        af[4] = (__bf16)m4; af[5] = (__bf16)m5; af[6] = (__bf16)m6; af[7] = (__bf16)m7;

        acc[0] = __builtin_amdgcn_mfma_f32_16x16x32_bf16(af, bf0, acc[0], 0, 0, 0);
        acc[1] = __builtin_amdgcn_mfma_f32_16x16x32_bf16(af, bf1, acc[1], 0, 0, 0);
    }

    // ---- norm: sum across the 4 quads -> every lane holds count of row l15 ----
    cnt += __shfl_xor(cnt, 16);
    cnt += __shfl_xor(cnt, 32);

    // C/D layout: row = quad*4 + r, col = l15-based f-column
    const int rbase = quad * 4;
    float rn[4];
#pragma unroll
    for (int r = 0; r < 4; ++r)
        rn[r] = 1.f / fmaxf(__shfl(cnt, rbase + r), 1.f);

    // ---- scale, write msg bf16 to LDS in [m][f] layout ----
#pragma unroll
    for (int ft = 0; ft < 2; ++ft) {
        int fcol = wf * 32 + ft * 16 + l15;
#pragma unroll
        for (int r = 0; r < 4; ++r)
            Ms[(rbase + r) * MP + fcol] = (__bf16)(acc[ft][r] * rn[r]);
    }
    __syncthreads();

    // ---- second GEMM: out[m][g] = sum_f msg[m][f] * W[g][f]; W direct from global (L2) ----
    fx4 acc2[2] = {};
#pragma unroll
    for (int ks = 0; ks < 4; ++ks) {
        bf16x8 af = *(const bf16x8*)&Ms[l15 * MP + ks * 32 + quad * 8];
#pragma unroll
        for (int gt = 0; gt < 2; ++gt) {
            int g = wf * 32 + gt * 16 + l15;
            bf16x8 wfr = *(const bf16x8*)&Wb[(size_t)g * F_ + ks * 32 + quad * 8];
            acc2[gt] = __builtin_amdgcn_mfma_f32_16x16x32_bf16(af, wfr, acc2[gt], 0, 0, 0);
        }
    }

    // ---- bias + relu + store ----
#pragma unroll
    for (int gt = 0; gt < 2; ++gt) {
        int g = wf * 32 + gt * 16 + l15;
        float bb = bias[g];
#pragma unroll
        for (int r = 0; r < 4; ++r) {
            int e = e0 + rbase + r;
            float v = acc2[gt][r] + bb;
            out[((size_t)b * E_ + e) * F_ + g] = fmaxf(v, 0.f);
        }
    }
}

extern "C" void kernel_launch(void* const* d_in, const int* in_sizes, int n_in,
                              void* d_out, int out_size, void* d_ws, size_t ws_size,
                              hipStream_t stream) {
    const float* node = (const float*)d_in[0];   // [B,N,F]
    const float* adj  = (const float*)d_in[1];   // [B,E,N]
    const float* W    = (const float*)d_in[2];   // [F,F]
    const float* bias = (const float*)d_in[3];   // [F]
    float* out = (float*)d_out;                  // [B,E,F]

    __bf16* nodeT = (__bf16*)d_ws;
    __bf16* Wb    = (__bf16*)((char*)d_ws + (size_t)B_ * F_ * N_ * 2);

    prep_node<<<512, 256, 0, stream>>>(node, nodeT);
    prep_w<<<16, 256, 0, stream>>>(W, Wb);
    v2h_main<<<1024, 256, 0, stream>>>(adj, nodeT, Wb, bias, out);
}

// Round 5
// 252.571 us; speedup vs baseline: 2.4306x; 1.1094x over previous
//
#include <hip/hip_runtime.h>
#include <hip/hip_bf16.h>

#define B_ 8
#define E_ 2048
#define N_ 2048
#define F_ 128

#define BM 16      // hyperedge rows per block
#define BK 64      // K chunk (elements)
#define MP 136     // msg LDS pitch

using bf16x8 = __bf16 __attribute__((ext_vector_type(8)));
using fx4    = float __attribute__((ext_vector_type(4)));

// ---------------- prep: node [B][N][F] f32 -> nodeT [B][F][N] bf16 ----------------
__global__ __launch_bounds__(256) void prep_node(const float* __restrict__ node,
                                                 __bf16* __restrict__ nodeT) {
    const int bid = blockIdx.x;          // 512 blocks
    const int b   = bid & 7;
    const int n0  = (bid >> 3) * 32;
    const int t   = threadIdx.x;
    const int f   = t & 127;
    const int nb  = n0 + (t >> 7) * 16;

    const float* src = node + ((size_t)b * N_ + nb) * F_ + f;
    __bf16 h[16];
#pragma unroll
    for (int i = 0; i < 16; ++i)
        h[i] = (__bf16)src[(size_t)i * F_];

    __bf16* dst = nodeT + ((size_t)b * F_ + f) * N_ + nb;
    *(uint4*)&dst[0] = *(const uint4*)&h[0];
    *(uint4*)&dst[8] = *(const uint4*)&h[8];
}

// ---------------- prep: W f32 -> bf16 ----------------
__global__ __launch_bounds__(256) void prep_w(const float* __restrict__ W,
                                              __bf16* __restrict__ Wb) {
    int idx = blockIdx.x * 256 + threadIdx.x;   // 0..4095
    float4 v = *(const float4*)&W[idx * 4];
    __bf16 o[4] = {(__bf16)v.x, (__bf16)v.y, (__bf16)v.z, (__bf16)v.w};
    *(uint2*)&Wb[idx * 4] = *(const uint2*)o;
}

// ---------------- main: async-DMA B staging (dbuf, swizzled), reg-staged A ----------------
__global__ __launch_bounds__(256, 4) void v2h_main(const float* __restrict__ adj,
                                                   const __bf16* __restrict__ nodeT,
                                                   const __bf16* __restrict__ Wb,
                                                   const float* __restrict__ bias,
                                                   float* __restrict__ out) {
    // Bs: [buf][f:128][k:64] bf16, UNPADDED (DMA layout), 16B granules XOR-swizzled:
    //   LDS slot s of row f holds global k-granule (s ^ (f&7)).
    __shared__ __align__(16) __bf16 Bs[2][128][64];      // 32 KB
    __shared__ __align__(16) __bf16 Ms[BM * MP];         // 4.3 KB

    const int t    = threadIdx.x;
    const int bid  = blockIdx.x;
    const int b    = bid & 7;            // batch -> XCD L2 locality for nodeT[b]
    const int e0   = (bid >> 3) * BM;
    const int w    = t >> 6;             // wave id = f-group (32 cols)
    const int lane = t & 63;
    const int l15  = lane & 15;
    const int quad = lane >> 4;

    const float*  aRow = adj + ((size_t)b * E_ + e0 + l15) * N_ + quad * 8;
    const __bf16* nTB  = nodeT + (size_t)b * F_ * N_;

    // DMA: 4 x 16B per thread fills one 128x64 chunk; dest = base + idx*16 (lane-contig)
    auto issue_dma = [&](int k0, int buf) {
#pragma unroll
        for (int p = 0; p < 4; ++p) {
            int idx = t + 256 * p;               // 0..1023
            int f   = idx >> 3;                  // 0..127
            int sl  = idx & 7;                   // LDS slot
            int g   = sl ^ (f & 7);              // global granule
            const __bf16* src = nTB + (size_t)f * N_ + k0 + g * 8;
            __bf16* dst = &Bs[buf][0][0] + (size_t)(w * 64 + 256 * p) * 8; // wave-uniform
            __builtin_amdgcn_global_load_lds(
                (const __attribute__((address_space(1))) void*)src,
                (__attribute__((address_space(3))) void*)dst, 16, 0, 0);
        }
    };

    fx4 acc[2] = {};
    float cnt = 0.f;

    // prologue: chunk 0 in flight + A regs for chunk 0
    issue_dma(0, 0);
    float4 aR0 = *(const float4*)(aRow + 0);
    float4 aR1 = *(const float4*)(aRow + 4);
    float4 aR2 = *(const float4*)(aRow + 32);
    float4 aR3 = *(const float4*)(aRow + 36);

    for (int k0 = 0; k0 < N_; k0 += BK) {
        const int buf = (k0 >> 6) & 1;
        __syncthreads();   // compiler's pre-barrier vmcnt(0): DMA(k0) + aR* complete

        const int kn = (k0 + BK) & (N_ - 1);     // wrap on last iter (harmless)
        issue_dma(kn, buf ^ 1);
        float4 aN0 = *(const float4*)(aRow + kn);
        float4 aN1 = *(const float4*)(aRow + kn + 4);
        float4 aN2 = *(const float4*)(aRow + kn + 32);
        float4 aN3 = *(const float4*)(aRow + kn + 36);

        // convert adj -> bf16 mask fragments + count
        bf16x8 af[2];
        {
            float m0 = (aR0.x == -1.f) ? 1.f : 0.f;
            float m1 = (aR0.y == -1.f) ? 1.f : 0.f;
            float m2 = (aR0.z == -1.f) ? 1.f : 0.f;
            float m3 = (aR0.w == -1.f) ? 1.f : 0.f;
            float m4 = (aR1.x == -1.f) ? 1.f : 0.f;
            float m5 = (aR1.y == -1.f) ? 1.f : 0.f;
            float m6 = (aR1.z == -1.f) ? 1.f : 0.f;
            float m7 = (aR1.w == -1.f) ? 1.f : 0.f;
            cnt += (m0 + m1) + (m2 + m3) + ((m4 + m5) + (m6 + m7));
            af[0][0] = (__bf16)m0; af[0][1] = (__bf16)m1; af[0][2] = (__bf16)m2; af[0][3] = (__bf16)m3;
            af[0][4] = (__bf16)m4; af[0][5] = (__bf16)m5; af[0][6] = (__bf16)m6; af[0][7] = (__bf16)m7;
        }
        {
            float m0 = (aR2.x == -1.f) ? 1.f : 0.f;
            float m1 = (aR2.y == -1.f) ? 1.f : 0.f;
            float m2 = (aR2.z == -1.f) ? 1.f : 0.f;
            float m3 = (aR2.w == -1.f) ? 1.f : 0.f;
            float m4 = (aR3.x == -1.f) ? 1.f : 0.f;
            float m5 = (aR3.y == -1.f) ? 1.f : 0.f;
            float m6 = (aR3.z == -1.f) ? 1.f : 0.f;
            float m7 = (aR3.w == -1.f) ? 1.f : 0.f;
            cnt += (m0 + m1) + (m2 + m3) + ((m4 + m5) + (m6 + m7));
            af[1][0] = (__bf16)m0; af[1][1] = (__bf16)m1; af[1][2] = (__bf16)m2; af[1][3] = (__bf16)m3;
            af[1][4] = (__bf16)m4; af[1][5] = (__bf16)m5; af[1][6] = (__bf16)m6; af[1][7] = (__bf16)m7;
        }

        // MFMA: B frag = row f, k-granule q = ks*4+quad, at swizzled slot q^(f&7)
#pragma unroll
        for (int ks = 0; ks < 2; ++ks) {
#pragma unroll
            for (int ft = 0; ft < 2; ++ft) {
                int f = w * 32 + ft * 16 + l15;
                int q = ks * 4 + quad;
                bf16x8 bfr = *(const bf16x8*)&Bs[buf][f][(q ^ (f & 7)) * 8];
                acc[ft] = __builtin_amdgcn_mfma_f32_16x16x32_bf16(af[ks], bfr, acc[ft], 0, 0, 0);
            }
        }

        aR0 = aN0; aR1 = aN1; aR2 = aN2; aR3 = aN3;
    }

    // ---- norm: reduce across quads; every lane then holds count of row l15 ----
    cnt += __shfl_xor(cnt, 16);
    cnt += __shfl_xor(cnt, 32);

    const int rbase = quad * 4;
    float rn[4];
#pragma unroll
    for (int r = 0; r < 4; ++r)
        rn[r] = 1.f / fmaxf(__shfl(cnt, rbase + r), 1.f);

    // ---- scale, write msg bf16 to LDS in [m][f] layout ----
#pragma unroll
    for (int ft = 0; ft < 2; ++ft) {
        int fcol = w * 32 + ft * 16 + l15;
#pragma unroll
        for (int r = 0; r < 4; ++r)
            Ms[(rbase + r) * MP + fcol] = (__bf16)(acc[ft][r] * rn[r]);
    }
    __syncthreads();   // also drains the last wrapped DMA before we leave

    // ---- second GEMM: out[m][g] = sum_f msg[m][f] * W[g][f]; W direct from L2 ----
    fx4 acc2[2] = {};
#pragma unroll
    for (int ks = 0; ks < 4; ++ks) {
        bf16x8 afm = *(const bf16x8*)&Ms[l15 * MP + ks * 32 + quad * 8];
#pragma unroll
        for (int gt = 0; gt < 2; ++gt) {
            int g = w * 32 + gt * 16 + l15;
            bf16x8 wfr = *(const bf16x8*)&Wb[(size_t)g * F_ + ks * 32 + quad * 8];
            acc2[gt] = __builtin_amdgcn_mfma_f32_16x16x32_bf16(afm, wfr, acc2[gt], 0, 0, 0);
        }
    }

    // ---- bias + relu + store ----
#pragma unroll
    for (int gt = 0; gt < 2; ++gt) {
        int g = w * 32 + gt * 16 + l15;
        float bb = bias[g];
#pragma unroll
        for (int r = 0; r < 4; ++r) {
            int e = e0 + rbase + r;
            float v = acc2[gt][r] + bb;
            out[((size_t)b * E_ + e) * F_ + g] = fmaxf(v, 0.f);
        }
    }
}

extern "C" void kernel_launch(void* const* d_in, const int* in_sizes, int n_in,
                              void* d_out, int out_size, void* d_ws, size_t ws_size,
                              hipStream_t stream) {
    const float* node = (const float*)d_in[0];   // [B,N,F]
    const float* adj  = (const float*)d_in[1];   // [B,E,N]
    const float* W    = (const float*)d_in[2];   // [F,F]
    const float* bias = (const float*)d_in[3];   // [F]
    float* out = (float*)d_out;                  // [B,E,F]

    __bf16* nodeT = (__bf16*)d_ws;
    __bf16* Wb    = (__bf16*)((char*)d_ws + (size_t)B_ * F_ * N_ * 2);

    prep_node<<<512, 256, 0, stream>>>(node, nodeT);
    prep_w<<<16, 256, 0, stream>>>(W, Wb);
    v2h_main<<<1024, 256, 0, stream>>>(adj, nodeT, Wb, bias, out);
}

// Round 6
// 230.596 us; speedup vs baseline: 2.6623x; 1.0953x over previous
//
#include <hip/hip_runtime.h>
#include <hip/hip_bf16.h>

#define B_ 8
#define E_ 2048
#define N_ 2048
#define F_ 128

#define BM 16      // hyperedge rows per block
#define BK 64      // K chunk (elements)
#define MP 136     // msg LDS pitch

using bf16x8 = __bf16 __attribute__((ext_vector_type(8)));
using fx4    = float __attribute__((ext_vector_type(4)));

// ---------------- prep: node [B][N][F] f32 -> nodeT [B][F][N] bf16 ----------------
__global__ __launch_bounds__(256) void prep_node(const float* __restrict__ node,
                                                 __bf16* __restrict__ nodeT) {
    const int bid = blockIdx.x;          // 512 blocks
    const int b   = bid & 7;
    const int n0  = (bid >> 3) * 32;
    const int t   = threadIdx.x;
    const int f   = t & 127;
    const int nb  = n0 + (t >> 7) * 16;

    const float* src = node + ((size_t)b * N_ + nb) * F_ + f;
    __bf16 h[16];
#pragma unroll
    for (int i = 0; i < 16; ++i)
        h[i] = (__bf16)src[(size_t)i * F_];

    __bf16* dst = nodeT + ((size_t)b * F_ + f) * N_ + nb;
    *(uint4*)&dst[0] = *(const uint4*)&h[0];
    *(uint4*)&dst[8] = *(const uint4*)&h[8];
}

// ---------------- prep: W f32 -> bf16 ----------------
__global__ __launch_bounds__(256) void prep_w(const float* __restrict__ W,
                                              __bf16* __restrict__ Wb) {
    int idx = blockIdx.x * 256 + threadIdx.x;   // 0..4095
    float4 v = *(const float4*)&W[idx * 4];
    __bf16 o[4] = {(__bf16)v.x, (__bf16)v.y, (__bf16)v.z, (__bf16)v.w};
    *(uint2*)&Wb[idx * 4] = *(const uint2*)o;
}

// ---------------- prep: adj row -> 256B bitmask (lane-transposed) + recip count ----
// One block per (b,e) row. Thread t handles n in [8t, 8t+8): builds a mask byte.
// Byte layout per row: pos = q*64 + m*2 + ks  where n = 64m + 32ks + 8q + j.
// -> main-kernel lane `quad` reads its 64 bytes contiguously at offset quad*64.
__global__ __launch_bounds__(256) void prep_adj(const float* __restrict__ adj,
                                                unsigned char* __restrict__ bitsT,
                                                float* __restrict__ rcount) {
    __shared__ __align__(16) unsigned char rowB[256];
    __shared__ float cw[4];
    const int row = blockIdx.x;            // b*E + e
    const int t   = threadIdx.x;

    const float* src = adj + (size_t)row * N_ + t * 8;
    float4 v0 = *(const float4*)src;
    float4 v1 = *(const float4*)(src + 4);
    unsigned m = 0;
    m |= (v0.x == -1.f) ? 1u   : 0u;
    m |= (v0.y == -1.f) ? 2u   : 0u;
    m |= (v0.z == -1.f) ? 4u   : 0u;
    m |= (v0.w == -1.f) ? 8u   : 0u;
    m |= (v1.x == -1.f) ? 16u  : 0u;
    m |= (v1.y == -1.f) ? 32u  : 0u;
    m |= (v1.z == -1.f) ? 64u  : 0u;
    m |= (v1.w == -1.f) ? 128u : 0u;

    const int q  = t & 3;
    const int ks = (t >> 2) & 1;
    const int mm = t >> 3;
    rowB[q * 64 + mm * 2 + ks] = (unsigned char)m;

    float c = (float)__popc(m);
#pragma unroll
    for (int s = 1; s < 64; s <<= 1) c += __shfl_xor(c, s);
    if ((t & 63) == 0) cw[t >> 6] = c;
    __syncthreads();

    if (t < 64) {
        unsigned d = *(const unsigned*)&rowB[t * 4];
        *(unsigned*)&bitsT[(size_t)row * 256 + t * 4] = d;
    }
    if (t == 0) {
        float tot = cw[0] + cw[1] + cw[2] + cw[3];
        rcount[row] = 1.f / fmaxf(tot, 1.f);
    }
}

// ---------------- main: bits-in-registers A, async-DMA B staging (dbuf, swizzled) ----
__global__ __launch_bounds__(256, 4) void v2h_main(const unsigned char* __restrict__ bitsT,
                                                   const __bf16* __restrict__ nodeT,
                                                   const __bf16* __restrict__ Wb,
                                                   const float* __restrict__ bias,
                                                   const float* __restrict__ rcount,
                                                   float* __restrict__ out) {
    __shared__ __align__(16) __bf16 Bs[2][128][64];      // 32 KB, swizzled DMA layout
    __shared__ __align__(16) __bf16 Ms[BM * MP];         // 4.3 KB

    const int t    = threadIdx.x;
    const int bid  = blockIdx.x;
    const int b    = bid & 7;            // batch -> XCD L2 locality for nodeT[b]
    const int e0   = (bid >> 3) * BM;
    const int w    = t >> 6;             // wave id = f-group (32 cols)
    const int lane = t & 63;
    const int l15  = lane & 15;
    const int quad = lane >> 4;

    const __bf16* nTB = nodeT + (size_t)b * F_ * N_;

    // DMA: 4 x 16B per thread fills one 128x64 chunk; 16B granules XOR-swizzled.
    auto issue_dma = [&](int k0, int buf) {
#pragma unroll
        for (int p = 0; p < 4; ++p) {
            int idx = t + 256 * p;               // 0..1023
            int f   = idx >> 3;                  // 0..127
            int sl  = idx & 7;                   // LDS slot
            int g   = sl ^ (f & 7);              // global granule
            const __bf16* src = nTB + (size_t)f * N_ + k0 + g * 8;
            __bf16* dst = &Bs[buf][0][0] + (size_t)(w * 64 + 256 * p) * 8; // wave-uniform
            __builtin_amdgcn_global_load_lds(
                (const __attribute__((address_space(1))) void*)src,
                (__attribute__((address_space(3))) void*)dst, 16, 0, 0);
        }
    };

    // ---- preload this lane's A bits: 64 contiguous bytes (whole K) ----
    const unsigned char* rbP = bitsT + ((size_t)b * E_ + e0 + l15) * 256 + quad * 64;
    uint4 rb0 = *(const uint4*)(rbP +  0);
    uint4 rb1 = *(const uint4*)(rbP + 16);
    uint4 rb2 = *(const uint4*)(rbP + 32);
    uint4 rb3 = *(const uint4*)(rbP + 48);
    unsigned rw[16] = {rb0.x, rb0.y, rb0.z, rb0.w, rb1.x, rb1.y, rb1.z, rb1.w,
                       rb2.x, rb2.y, rb2.z, rb2.w, rb3.x, rb3.y, rb3.z, rb3.w};

    auto unpack = [](unsigned byte) -> bf16x8 {
        union { unsigned u[4]; bf16x8 v; } r;
        r.u[0] = ((byte &   1u) ? 0x3F80u : 0u) | ((byte &   2u) ? 0x3F800000u : 0u);
        r.u[1] = ((byte &   4u) ? 0x3F80u : 0u) | ((byte &   8u) ? 0x3F800000u : 0u);
        r.u[2] = ((byte &  16u) ? 0x3F80u : 0u) | ((byte &  32u) ? 0x3F800000u : 0u);
        r.u[3] = ((byte &  64u) ? 0x3F80u : 0u) | ((byte & 128u) ? 0x3F800000u : 0u);
        return r.v;
    };

    fx4 acc[2] = {};

    issue_dma(0, 0);

#pragma unroll
    for (int m = 0; m < 32; ++m) {
        const int buf = m & 1;
        __syncthreads();                         // drains DMA(m) issued last iter

        issue_dma(((m + 1) & 31) * BK, buf ^ 1); // wrap on last iter (harmless)

        const unsigned word = rw[m >> 1];
        const int sh = 16 * (m & 1);
        bf16x8 af0 = unpack((word >> sh) & 255u);
        bf16x8 af1 = unpack((word >> (sh + 8)) & 255u);

        // B frag = row f, k-granule qg = ks*4+quad, at swizzled slot qg^(f&7)
#pragma unroll
        for (int ft = 0; ft < 2; ++ft) {
            int f  = w * 32 + ft * 16 + l15;
            int q0 = quad ^ (f & 7);
            int q1 = (4 + quad) ^ (f & 7);
            bf16x8 b0 = *(const bf16x8*)&Bs[buf][f][q0 * 8];
            acc[ft] = __builtin_amdgcn_mfma_f32_16x16x32_bf16(af0, b0, acc[ft], 0, 0, 0);
            bf16x8 b1 = *(const bf16x8*)&Bs[buf][f][q1 * 8];
            acc[ft] = __builtin_amdgcn_mfma_f32_16x16x32_bf16(af1, b1, acc[ft], 0, 0, 0);
        }
    }

    // ---- scale by precomputed 1/count, write msg bf16 to LDS in [m][f] layout ----
    const int rbase = quad * 4;
    float rn[4];
#pragma unroll
    for (int r = 0; r < 4; ++r)
        rn[r] = rcount[(size_t)b * E_ + e0 + rbase + r];
#pragma unroll
    for (int ft = 0; ft < 2; ++ft) {
        int fcol = w * 32 + ft * 16 + l15;
#pragma unroll
        for (int r = 0; r < 4; ++r)
            Ms[(rbase + r) * MP + fcol] = (__bf16)(acc[ft][r] * rn[r]);
    }
    __syncthreads();   // also keeps last wrapped DMA harmless

    // ---- second GEMM: out[m][g] = sum_f msg[m][f] * W[g][f]; W direct from L2 ----
    fx4 acc2[2] = {};
#pragma unroll
    for (int ks = 0; ks < 4; ++ks) {
        bf16x8 afm = *(const bf16x8*)&Ms[l15 * MP + ks * 32 + quad * 8];
#pragma unroll
        for (int gt = 0; gt < 2; ++gt) {
            int g = w * 32 + gt * 16 + l15;
            bf16x8 wfr = *(const bf16x8*)&Wb[(size_t)g * F_ + ks * 32 + quad * 8];
            acc2[gt] = __builtin_amdgcn_mfma_f32_16x16x32_bf16(afm, wfr, acc2[gt], 0, 0, 0);
        }
    }

    // ---- bias + relu + store ----
#pragma unroll
    for (int gt = 0; gt < 2; ++gt) {
        int g = w * 32 + gt * 16 + l15;
        float bb = bias[g];
#pragma unroll
        for (int r = 0; r < 4; ++r) {
            int e = e0 + rbase + r;
            float v = acc2[gt][r] + bb;
            out[((size_t)b * E_ + e) * F_ + g] = fmaxf(v, 0.f);
        }
    }
}

extern "C" void kernel_launch(void* const* d_in, const int* in_sizes, int n_in,
                              void* d_out, int out_size, void* d_ws, size_t ws_size,
                              hipStream_t stream) {
    const float* node = (const float*)d_in[0];   // [B,N,F]
    const float* adj  = (const float*)d_in[1];   // [B,E,N]
    const float* W    = (const float*)d_in[2];   // [F,F]
    const float* bias = (const float*)d_in[3];   // [F]
    float* out = (float*)d_out;                  // [B,E,F]

    char* ws = (char*)d_ws;
    __bf16*        nodeT = (__bf16*)ws;                                   // 8 MB
    __bf16*        Wb    = (__bf16*)(ws + 8 * 1024 * 1024);               // 32 KB
    unsigned char* bitsT = (unsigned char*)(ws + 8 * 1024 * 1024 + 65536);// 4 MB
    float*         rcnt  = (float*)(ws + 12 * 1024 * 1024 + 65536);       // 64 KB

    prep_node<<<512, 256, 0, stream>>>(node, nodeT);
    prep_w<<<16, 256, 0, stream>>>(W, Wb);
    prep_adj<<<B_ * E_, 256, 0, stream>>>(adj, bitsT, rcnt);
    v2h_main<<<1024, 256, 0, stream>>>(bitsT, nodeT, Wb, bias, rcnt, out);
}

// Round 7
// 221.464 us; speedup vs baseline: 2.7721x; 1.0412x over previous
//
#include <hip/hip_runtime.h>
#include <hip/hip_bf16.h>

#define B_ 8
#define E_ 2048
#define N_ 2048
#define F_ 128

#define BM 32      // hyperedge rows per block (2 m-tiles of 16)
#define BK 64      // K chunk (elements)
#define MP 136     // msg LDS pitch

using bf16x8 = __bf16 __attribute__((ext_vector_type(8)));
using fx4    = float __attribute__((ext_vector_type(4)));

// ---------------- fused prep: node transpose + W convert + adj bit-pack ----------------
// blocks [0,512): node [B][N][F] f32 -> nodeT [B][F][N] bf16 (register transpose)
// blocks [512,528): W f32 -> bf16
// blocks [528, 528+16384): adj row -> 256B lane-transposed bitmask + recip count
__global__ __launch_bounds__(256) void prep_all(const float* __restrict__ node,
                                                const float* __restrict__ adj,
                                                const float* __restrict__ W,
                                                __bf16* __restrict__ nodeT,
                                                __bf16* __restrict__ Wb,
                                                unsigned char* __restrict__ bitsT,
                                                float* __restrict__ rcount) {
    __shared__ __align__(16) unsigned char rowB[256];
    __shared__ float cw[4];
    const int bid = blockIdx.x;
    const int t   = threadIdx.x;

    if (bid < 512) {
        // ---- node transpose+convert ----
        const int b  = bid & 7;
        const int n0 = (bid >> 3) * 32;
        const int f  = t & 127;
        const int nb = n0 + (t >> 7) * 16;
        const float* src = node + ((size_t)b * N_ + nb) * F_ + f;
        __bf16 h[16];
#pragma unroll
        for (int i = 0; i < 16; ++i)
            h[i] = (__bf16)src[(size_t)i * F_];
        __bf16* dst = nodeT + ((size_t)b * F_ + f) * N_ + nb;
        *(uint4*)&dst[0] = *(const uint4*)&h[0];
        *(uint4*)&dst[8] = *(const uint4*)&h[8];
    } else if (bid < 528) {
        // ---- W convert ----
        int idx = (bid - 512) * 256 + t;        // 0..4095
        float4 v = *(const float4*)&W[idx * 4];
        __bf16 o[4] = {(__bf16)v.x, (__bf16)v.y, (__bf16)v.z, (__bf16)v.w};
        *(uint2*)&Wb[idx * 4] = *(const uint2*)o;
    } else {
        // ---- adj bit-pack: one block per (b,e) row ----
        // Byte pos = q*64 + m*2 + ks where n = 64m + 32ks + 8q + j.
        const int row = bid - 528;              // b*E + e
        const float* src = adj + (size_t)row * N_ + t * 8;
        float4 v0 = *(const float4*)src;
        float4 v1 = *(const float4*)(src + 4);
        unsigned m = 0;
        m |= (v0.x == -1.f) ? 1u   : 0u;
        m |= (v0.y == -1.f) ? 2u   : 0u;
        m |= (v0.z == -1.f) ? 4u   : 0u;
        m |= (v0.w == -1.f) ? 8u   : 0u;
        m |= (v1.x == -1.f) ? 16u  : 0u;
        m |= (v1.y == -1.f) ? 32u  : 0u;
        m |= (v1.z == -1.f) ? 64u  : 0u;
        m |= (v1.w == -1.f) ? 128u : 0u;

        const int q  = t & 3;
        const int ks = (t >> 2) & 1;
        const int mm = t >> 3;
        rowB[q * 64 + mm * 2 + ks] = (unsigned char)m;

        float c = (float)__popc(m);
#pragma unroll
        for (int s = 1; s < 64; s <<= 1) c += __shfl_xor(c, s);
        if ((t & 63) == 0) cw[t >> 6] = c;
        __syncthreads();

        if (t < 64) {
            unsigned d = *(const unsigned*)&rowB[t * 4];
            *(unsigned*)&bitsT[(size_t)row * 256 + t * 4] = d;
        }
        if (t == 0) {
            float tot = cw[0] + cw[1] + cw[2] + cw[3];
            rcount[row] = 1.f / fmaxf(tot, 1.f);
        }
    }
}

// ---------------- main: BM=32, bits-in-registers A (2 rows/lane), DMA B (dbuf) ----------
__global__ __launch_bounds__(256, 2) void v2h_main(const unsigned char* __restrict__ bitsT,
                                                   const __bf16* __restrict__ nodeT,
                                                   const __bf16* __restrict__ Wb,
                                                   const float* __restrict__ bias,
                                                   const float* __restrict__ rcount,
                                                   float* __restrict__ out) {
    __shared__ __align__(16) __bf16 Bs[2][128][64];      // 32 KB, swizzled DMA layout
    __shared__ __align__(16) __bf16 Ms[BM * MP];         // 8.7 KB

    const int t    = threadIdx.x;
    const int bid  = blockIdx.x;
    const int b    = bid & 7;            // batch -> XCD L2 locality for nodeT[b]
    const int e0   = (bid >> 3) * BM;
    const int w    = t >> 6;             // wave id = f-group (32 cols)
    const int lane = t & 63;
    const int l15  = lane & 15;
    const int quad = lane >> 4;

    const __bf16* nTB = nodeT + (size_t)b * F_ * N_;

    auto issue_dma = [&](int k0, int buf) {
#pragma unroll
        for (int p = 0; p < 4; ++p) {
            int idx = t + 256 * p;               // 0..1023
            int f   = idx >> 3;                  // 0..127
            int sl  = idx & 7;                   // LDS slot
            int g   = sl ^ (f & 7);              // global granule
            const __bf16* src = nTB + (size_t)f * N_ + k0 + g * 8;
            __bf16* dst = &Bs[buf][0][0] + (size_t)(w * 64 + 256 * p) * 8; // wave-uniform
            __builtin_amdgcn_global_load_lds(
                (const __attribute__((address_space(1))) void*)src,
                (__attribute__((address_space(3))) void*)dst, 16, 0, 0);
        }
    };

    // ---- preload A bits for rows (e0+l15) and (e0+16+l15): 64 B each ----
    const unsigned char* rpA = bitsT + ((size_t)b * E_ + e0 + l15) * 256 + quad * 64;
    const unsigned char* rpB = rpA + 16 * 256;
    uint4 ra0 = *(const uint4*)(rpA +  0), ra1 = *(const uint4*)(rpA + 16);
    uint4 ra2 = *(const uint4*)(rpA + 32), ra3 = *(const uint4*)(rpA + 48);
    uint4 rb0 = *(const uint4*)(rpB +  0), rb1 = *(const uint4*)(rpB + 16);
    uint4 rb2 = *(const uint4*)(rpB + 32), rb3 = *(const uint4*)(rpB + 48);
    unsigned rwA[16] = {ra0.x, ra0.y, ra0.z, ra0.w, ra1.x, ra1.y, ra1.z, ra1.w,
                        ra2.x, ra2.y, ra2.z, ra2.w, ra3.x, ra3.y, ra3.z, ra3.w};
    unsigned rwB[16] = {rb0.x, rb0.y, rb0.z, rb0.w, rb1.x, rb1.y, rb1.z, rb1.w,
                        rb2.x, rb2.y, rb2.z, rb2.w, rb3.x, rb3.y, rb3.z, rb3.w};

    auto unpack = [](unsigned byte) -> bf16x8 {
        union { unsigned u[4]; bf16x8 v; } r;
        r.u[0] = ((byte &   1u) ? 0x3F80u : 0u) | ((byte &   2u) ? 0x3F800000u : 0u);
        r.u[1] = ((byte &   4u) ? 0x3F80u : 0u) | ((byte &   8u) ? 0x3F800000u : 0u);
        r.u[2] = ((byte &  16u) ? 0x3F80u : 0u) | ((byte &  32u) ? 0x3F800000u : 0u);
        r.u[3] = ((byte &  64u) ? 0x3F80u : 0u) | ((byte & 128u) ? 0x3F800000u : 0u);
        return r.v;
    };

    fx4 accA[2] = {};    // m-tile 0 (rows e0..e0+15), ft 0..1
    fx4 accB[2] = {};    // m-tile 1 (rows e0+16..e0+31)

    issue_dma(0, 0);

#pragma unroll
    for (int m = 0; m < 32; ++m) {
        const int buf = m & 1;
        __syncthreads();                         // drains DMA(m) issued last iter

        issue_dma(((m + 1) & 31) * BK, buf ^ 1); // wrap on last iter (harmless)

        const int sh = 16 * (m & 1);
        const unsigned wA = rwA[m >> 1] >> sh;
        const unsigned wB = rwB[m >> 1] >> sh;
        bf16x8 afA0 = unpack(wA & 255u);
        bf16x8 afA1 = unpack((wA >> 8) & 255u);
        bf16x8 afB0 = unpack(wB & 255u);
        bf16x8 afB1 = unpack((wB >> 8) & 255u);

        // B frag = row f, k-granule qg = ks*4+quad, at swizzled slot qg^(f&7);
        // each B frag feeds both m-tiles.
#pragma unroll
        for (int ft = 0; ft < 2; ++ft) {
            int f  = w * 32 + ft * 16 + l15;
            int q0 = quad ^ (f & 7);
            int q1 = (4 + quad) ^ (f & 7);
            bf16x8 b0 = *(const bf16x8*)&Bs[buf][f][q0 * 8];
            accA[ft] = __builtin_amdgcn_mfma_f32_16x16x32_bf16(afA0, b0, accA[ft], 0, 0, 0);
            accB[ft] = __builtin_amdgcn_mfma_f32_16x16x32_bf16(afB0, b0, accB[ft], 0, 0, 0);
            bf16x8 b1 = *(const bf16x8*)&Bs[buf][f][q1 * 8];
            accA[ft] = __builtin_amdgcn_mfma_f32_16x16x32_bf16(afA1, b1, accA[ft], 0, 0, 0);
            accB[ft] = __builtin_amdgcn_mfma_f32_16x16x32_bf16(afB1, b1, accB[ft], 0, 0, 0);
        }
    }

    // ---- scale by precomputed 1/count, write msg bf16 to LDS in [m][f] layout ----
    const int rbase = quad * 4;
    const float* rcB = rcount + (size_t)b * E_ + e0;
    float rnA[4], rnB[4];
#pragma unroll
    for (int r = 0; r < 4; ++r) {
        rnA[r] = rcB[rbase + r];
        rnB[r] = rcB[16 + rbase + r];
    }
#pragma unroll
    for (int ft = 0; ft < 2; ++ft) {
        int fcol = w * 32 + ft * 16 + l15;
#pragma unroll
        for (int r = 0; r < 4; ++r) {
            Ms[(rbase + r) * MP + fcol]      = (__bf16)(accA[ft][r] * rnA[r]);
            Ms[(16 + rbase + r) * MP + fcol] = (__bf16)(accB[ft][r] * rnB[r]);
        }
    }
    __syncthreads();

    // ---- second GEMM: out[m][g] = sum_f msg[m][f] * W[g][f]; W direct from L2 ----
    fx4 acc2A[2] = {}, acc2B[2] = {};
#pragma unroll
    for (int ks = 0; ks < 4; ++ks) {
        bf16x8 afmA = *(const bf16x8*)&Ms[l15 * MP + ks * 32 + quad * 8];
        bf16x8 afmB = *(const bf16x8*)&Ms[(16 + l15) * MP + ks * 32 + quad * 8];
#pragma unroll
        for (int gt = 0; gt < 2; ++gt) {
            int g = w * 32 + gt * 16 + l15;
            bf16x8 wfr = *(const bf16x8*)&Wb[(size_t)g * F_ + ks * 32 + quad * 8];
            acc2A[gt] = __builtin_amdgcn_mfma_f32_16x16x32_bf16(afmA, wfr, acc2A[gt], 0, 0, 0);
            acc2B[gt] = __builtin_amdgcn_mfma_f32_16x16x32_bf16(afmB, wfr, acc2B[gt], 0, 0, 0);
        }
    }

    // ---- bias + relu + store (both m-tiles) ----
#pragma unroll
    for (int gt = 0; gt < 2; ++gt) {
        int g = w * 32 + gt * 16 + l15;
        float bb = bias[g];
#pragma unroll
        for (int r = 0; r < 4; ++r) {
            int e = e0 + rbase + r;
            float vA = acc2A[gt][r] + bb;
            float vB = acc2B[gt][r] + bb;
            out[((size_t)b * E_ + e) * F_ + g]      = fmaxf(vA, 0.f);
            out[((size_t)b * E_ + e + 16) * F_ + g] = fmaxf(vB, 0.f);
        }
    }
}

extern "C" void kernel_launch(void* const* d_in, const int* in_sizes, int n_in,
                              void* d_out, int out_size, void* d_ws, size_t ws_size,
                              hipStream_t stream) {
    const float* node = (const float*)d_in[0];   // [B,N,F]
    const float* adj  = (const float*)d_in[1];   // [B,E,N]
    const float* W    = (const float*)d_in[2];   // [F,F]
    const float* bias = (const float*)d_in[3];   // [F]
    float* out = (float*)d_out;                  // [B,E,F]

    char* ws = (char*)d_ws;
    __bf16*        nodeT = (__bf16*)ws;                                   // 8 MB
    __bf16*        Wb    = (__bf16*)(ws + 8 * 1024 * 1024);               // 32 KB
    unsigned char* bitsT = (unsigned char*)(ws + 8 * 1024 * 1024 + 65536);// 4 MB
    float*         rcnt  = (float*)(ws + 12 * 1024 * 1024 + 65536);       // 64 KB

    prep_all<<<528 + B_ * E_, 256, 0, stream>>>(node, adj, W, nodeT, Wb, bitsT, rcnt);
    v2h_main<<<512, 256, 0, stream>>>(bitsT, nodeT, Wb, bias, rcnt, out);
}

// Round 8
// 218.837 us; speedup vs baseline: 2.8053x; 1.0120x over previous
//
#include <hip/hip_runtime.h>
#include <hip/hip_bf16.h>

#define B_ 8
#define E_ 2048
#define N_ 2048
#define F_ 128

#define BM 64      // hyperedge rows per block (4 m-tiles of 16)
#define MT 4       // m-tiles
#define BK 64      // K chunk (elements)
#define MP 136     // msg LDS pitch

using bf16x8 = __bf16 __attribute__((ext_vector_type(8)));
using fx4    = float __attribute__((ext_vector_type(4)));

// ---------------- fused prep: node transpose + W convert + adj bit-pack ----------------
__global__ __launch_bounds__(256) void prep_all(const float* __restrict__ node,
                                                const float* __restrict__ adj,
                                                const float* __restrict__ W,
                                                __bf16* __restrict__ nodeT,
                                                __bf16* __restrict__ Wb,
                                                unsigned char* __restrict__ bitsT,
                                                float* __restrict__ rcount) {
    __shared__ __align__(16) unsigned char rowB[256];
    __shared__ float cw[4];
    const int bid = blockIdx.x;
    const int t   = threadIdx.x;

    if (bid < 512) {
        // ---- node transpose+convert ----
        const int b  = bid & 7;
        const int n0 = (bid >> 3) * 32;
        const int f  = t & 127;
        const int nb = n0 + (t >> 7) * 16;
        const float* src = node + ((size_t)b * N_ + nb) * F_ + f;
        __bf16 h[16];
#pragma unroll
        for (int i = 0; i < 16; ++i)
            h[i] = (__bf16)src[(size_t)i * F_];
        __bf16* dst = nodeT + ((size_t)b * F_ + f) * N_ + nb;
        *(uint4*)&dst[0] = *(const uint4*)&h[0];
        *(uint4*)&dst[8] = *(const uint4*)&h[8];
    } else if (bid < 528) {
        // ---- W convert ----
        int idx = (bid - 512) * 256 + t;        // 0..4095
        float4 v = *(const float4*)&W[idx * 4];
        __bf16 o[4] = {(__bf16)v.x, (__bf16)v.y, (__bf16)v.z, (__bf16)v.w};
        *(uint2*)&Wb[idx * 4] = *(const uint2*)o;
    } else {
        // ---- adj bit-pack: one block per (b,e) row ----
        // Byte pos = q*64 + m*2 + ks where n = 64m + 32ks + 8q + j.
        const int row = bid - 528;              // b*E + e
        const float* src = adj + (size_t)row * N_ + t * 8;
        float4 v0 = *(const float4*)src;
        float4 v1 = *(const float4*)(src + 4);
        unsigned m = 0;
        m |= (v0.x == -1.f) ? 1u   : 0u;
        m |= (v0.y == -1.f) ? 2u   : 0u;
        m |= (v0.z == -1.f) ? 4u   : 0u;
        m |= (v0.w == -1.f) ? 8u   : 0u;
        m |= (v1.x == -1.f) ? 16u  : 0u;
        m |= (v1.y == -1.f) ? 32u  : 0u;
        m |= (v1.z == -1.f) ? 64u  : 0u;
        m |= (v1.w == -1.f) ? 128u : 0u;

        const int q  = t & 3;
        const int ks = (t >> 2) & 1;
        const int mm = t >> 3;
        rowB[q * 64 + mm * 2 + ks] = (unsigned char)m;

        float c = (float)__popc(m);
#pragma unroll
        for (int s = 1; s < 64; s <<= 1) c += __shfl_xor(c, s);
        if ((t & 63) == 0) cw[t >> 6] = c;
        __syncthreads();

        if (t < 64) {
            unsigned d = *(const unsigned*)&rowB[t * 4];
            *(unsigned*)&bitsT[(size_t)row * 256 + t * 4] = d;
        }
        if (t == 0) {
            float tot = cw[0] + cw[1] + cw[2] + cw[3];
            rcount[row] = 1.f / fmaxf(tot, 1.f);
        }
    }
}

// ---------------- main: BM=64, bits-in-registers A (4 rows/lane), DMA B (dbuf) ----------
__global__ __launch_bounds__(256, 1) void v2h_main(const unsigned char* __restrict__ bitsT,
                                                   const __bf16* __restrict__ nodeT,
                                                   const __bf16* __restrict__ Wb,
                                                   const float* __restrict__ bias,
                                                   const float* __restrict__ rcount,
                                                   float* __restrict__ out) {
    // Bs double buffer (2 x 128 x 64 bf16 = 32 KB). Ms (64 x MP = 17.4 KB) aliases
    // the front of smem: safe because the wrapped DMA is skipped on the last iter
    // and Bs[0]'s final reads complete before the m=31 barrier.
    __shared__ __align__(16) __bf16 smem[2 * 128 * 64];
    __bf16 (*Bs)[128][64] = (__bf16 (*)[128][64])smem;
    __bf16* Ms = smem;

    const int t    = threadIdx.x;
    const int bid  = blockIdx.x;
    const int b    = bid & 7;            // batch -> XCD L2 locality for nodeT[b]
    const int e0   = (bid >> 3) * BM;    // bid>>3 in 0..31
    const int w    = t >> 6;             // wave id = f-group (32 cols)
    const int lane = t & 63;
    const int l15  = lane & 15;
    const int quad = lane >> 4;

    const __bf16* nTB = nodeT + (size_t)b * F_ * N_;

    auto issue_dma = [&](int k0, int buf) {
#pragma unroll
        for (int p = 0; p < 4; ++p) {
            int idx = t + 256 * p;               // 0..1023
            int f   = idx >> 3;                  // 0..127
            int sl  = idx & 7;                   // LDS slot
            int g   = sl ^ (f & 7);              // global granule
            const __bf16* src = nTB + (size_t)f * N_ + k0 + g * 8;
            __bf16* dst = &Bs[buf][0][0] + (size_t)(w * 64 + 256 * p) * 8; // wave-uniform
            __builtin_amdgcn_global_load_lds(
                (const __attribute__((address_space(1))) void*)src,
                (__attribute__((address_space(3))) void*)dst, 16, 0, 0);
        }
    };

    // ---- preload A bits for rows e0 + mt*16 + l15 (mt=0..3): 64 B each ----
    unsigned rw[MT][16];
#pragma unroll
    for (int mt = 0; mt < MT; ++mt) {
        const unsigned char* rp = bitsT + ((size_t)b * E_ + e0 + mt * 16 + l15) * 256 + quad * 64;
        uint4 r0 = *(const uint4*)(rp +  0), r1 = *(const uint4*)(rp + 16);
        uint4 r2 = *(const uint4*)(rp + 32), r3 = *(const uint4*)(rp + 48);
        rw[mt][0] = r0.x; rw[mt][1] = r0.y; rw[mt][2]  = r0.z; rw[mt][3]  = r0.w;
        rw[mt][4] = r1.x; rw[mt][5] = r1.y; rw[mt][6]  = r1.z; rw[mt][7]  = r1.w;
        rw[mt][8] = r2.x; rw[mt][9] = r2.y; rw[mt][10] = r2.z; rw[mt][11] = r2.w;
        rw[mt][12] = r3.x; rw[mt][13] = r3.y; rw[mt][14] = r3.z; rw[mt][15] = r3.w;
    }

    auto unpack = [](unsigned byte) -> bf16x8 {
        union { unsigned u[4]; bf16x8 v; } r;
        r.u[0] = ((byte &   1u) ? 0x3F80u : 0u) | ((byte &   2u) ? 0x3F800000u : 0u);
        r.u[1] = ((byte &   4u) ? 0x3F80u : 0u) | ((byte &   8u) ? 0x3F800000u : 0u);
        r.u[2] = ((byte &  16u) ? 0x3F80u : 0u) | ((byte &  32u) ? 0x3F800000u : 0u);
        r.u[3] = ((byte &  64u) ? 0x3F80u : 0u) | ((byte & 128u) ? 0x3F800000u : 0u);
        return r.v;
    };

    fx4 acc[MT][2] = {};

    issue_dma(0, 0);

#pragma unroll
    for (int m = 0; m < 32; ++m) {
        const int buf = m & 1;
        __syncthreads();                         // drains DMA(m) issued last iter

        if (m != 31)
            issue_dma((m + 1) * BK, buf ^ 1);

        const int sh = 16 * (m & 1);
        bf16x8 af0[MT], af1[MT];
#pragma unroll
        for (int mt = 0; mt < MT; ++mt) {
            const unsigned wd = rw[mt][m >> 1] >> sh;
            af0[mt] = unpack(wd & 255u);
            af1[mt] = unpack((wd >> 8) & 255u);
        }

        // B frag = row f, k-granule qg = ks*4+quad, at swizzled slot qg^(f&7);
        // each B frag feeds all 4 m-tiles.
#pragma unroll
        for (int ft = 0; ft < 2; ++ft) {
            int f  = w * 32 + ft * 16 + l15;
            int q0 = quad ^ (f & 7);
            int q1 = (4 + quad) ^ (f & 7);
            bf16x8 b0 = *(const bf16x8*)&Bs[buf][f][q0 * 8];
#pragma unroll
            for (int mt = 0; mt < MT; ++mt)
                acc[mt][ft] = __builtin_amdgcn_mfma_f32_16x16x32_bf16(af0[mt], b0, acc[mt][ft], 0, 0, 0);
            bf16x8 b1 = *(const bf16x8*)&Bs[buf][f][q1 * 8];
#pragma unroll
            for (int mt = 0; mt < MT; ++mt)
                acc[mt][ft] = __builtin_amdgcn_mfma_f32_16x16x32_bf16(af1[mt], b1, acc[mt][ft], 0, 0, 0);
        }
    }

    // ---- scale by precomputed 1/count, write msg bf16 to LDS in [m][f] layout ----
    const int rbase = quad * 4;
    const float* rcB = rcount + (size_t)b * E_ + e0;
    float4 rn[MT];
#pragma unroll
    for (int mt = 0; mt < MT; ++mt)
        rn[mt] = *(const float4*)&rcB[mt * 16 + rbase];

#pragma unroll
    for (int ft = 0; ft < 2; ++ft) {
        int fcol = w * 32 + ft * 16 + l15;
#pragma unroll
        for (int mt = 0; mt < MT; ++mt) {
            const float* rr = (const float*)&rn[mt];
#pragma unroll
            for (int r = 0; r < 4; ++r)
                Ms[(mt * 16 + rbase + r) * MP + fcol] = (__bf16)(acc[mt][ft][r] * rr[r]);
        }
    }
    __syncthreads();

    // ---- second GEMM: out[m][g] = sum_f msg[m][f] * W[g][f]; W direct from L2 ----
    fx4 acc2[MT][2] = {};
#pragma unroll
    for (int ks = 0; ks < 4; ++ks) {
        bf16x8 afm[MT];
#pragma unroll
        for (int mt = 0; mt < MT; ++mt)
            afm[mt] = *(const bf16x8*)&Ms[(mt * 16 + l15) * MP + ks * 32 + quad * 8];
#pragma unroll
        for (int gt = 0; gt < 2; ++gt) {
            int g = w * 32 + gt * 16 + l15;
            bf16x8 wfr = *(const bf16x8*)&Wb[(size_t)g * F_ + ks * 32 + quad * 8];
#pragma unroll
            for (int mt = 0; mt < MT; ++mt)
                acc2[mt][gt] = __builtin_amdgcn_mfma_f32_16x16x32_bf16(afm[mt], wfr, acc2[mt][gt], 0, 0, 0);
        }
    }

    // ---- bias + relu + store (all m-tiles) ----
#pragma unroll
    for (int gt = 0; gt < 2; ++gt) {
        int g = w * 32 + gt * 16 + l15;
        float bb = bias[g];
#pragma unroll
        for (int mt = 0; mt < MT; ++mt) {
#pragma unroll
            for (int r = 0; r < 4; ++r) {
                int e = e0 + mt * 16 + rbase + r;
                float v = acc2[mt][gt][r] + bb;
                out[((size_t)b * E_ + e) * F_ + g] = fmaxf(v, 0.f);
            }
        }
    }
}

extern "C" void kernel_launch(void* const* d_in, const int* in_sizes, int n_in,
                              void* d_out, int out_size, void* d_ws, size_t ws_size,
                              hipStream_t stream) {
    const float* node = (const float*)d_in[0];   // [B,N,F]
    const float* adj  = (const float*)d_in[1];   // [B,E,N]
    const float* W    = (const float*)d_in[2];   // [F,F]
    const float* bias = (const float*)d_in[3];   // [F]
    float* out = (float*)d_out;                  // [B,E,F]

    char* ws = (char*)d_ws;
    __bf16*        nodeT = (__bf16*)ws;                                   // 8 MB
    __bf16*        Wb    = (__bf16*)(ws + 8 * 1024 * 1024);               // 32 KB
    unsigned char* bitsT = (unsigned char*)(ws + 8 * 1024 * 1024 + 65536);// 4 MB
    float*         rcnt  = (float*)(ws + 12 * 1024 * 1024 + 65536);       // 64 KB

    prep_all<<<528 + B_ * E_, 256, 0, stream>>>(node, adj, W, nodeT, Wb, bitsT, rcnt);
    v2h_main<<<256, 256, 0, stream>>>(bitsT, nodeT, Wb, bias, rcnt, out);
}

// Round 9
// 210.558 us; speedup vs baseline: 2.9156x; 1.0393x over previous
//
#include <hip/hip_runtime.h>
#include <hip/hip_bf16.h>

#define B_ 8
#define E_ 2048
#define N_ 2048
#define F_ 128

#define BM 64      // hyperedge rows per block (4 m-tiles of 16)
#define MT 4       // m-tiles
#define BK 64      // K chunk (elements)
#define MP 136     // msg LDS pitch

using bf16x8 = __bf16 __attribute__((ext_vector_type(8)));
using fx4    = float __attribute__((ext_vector_type(4)));

// ---------------- prep: node transpose + W convert (adj handled in main now) --------
__global__ __launch_bounds__(256) void prep_all(const float* __restrict__ node,
                                                const float* __restrict__ W,
                                                __bf16* __restrict__ nodeT,
                                                __bf16* __restrict__ Wb) {
    const int bid = blockIdx.x;
    const int t   = threadIdx.x;

    if (bid < 512) {
        // ---- node [B][N][F] f32 -> nodeT [B][F][N] bf16 (register transpose) ----
        const int b  = bid & 7;
        const int n0 = (bid >> 3) * 32;
        const int f  = t & 127;
        const int nb = n0 + (t >> 7) * 16;
        const float* src = node + ((size_t)b * N_ + nb) * F_ + f;
        __bf16 h[16];
#pragma unroll
        for (int i = 0; i < 16; ++i)
            h[i] = (__bf16)src[(size_t)i * F_];
        __bf16* dst = nodeT + ((size_t)b * F_ + f) * N_ + nb;
        *(uint4*)&dst[0] = *(const uint4*)&h[0];
        *(uint4*)&dst[8] = *(const uint4*)&h[8];
    } else {
        // ---- W f32 -> bf16 ----
        int idx = (bid - 512) * 256 + t;        // 0..4095
        float4 v = *(const float4*)&W[idx * 4];
        __bf16 o[4] = {(__bf16)v.x, (__bf16)v.y, (__bf16)v.z, (__bf16)v.w};
        *(uint2*)&Wb[idx * 4] = *(const uint2*)o;
    }
}

// ---------------- main: fused adj-stream + bitpack + GEMM1 + norm + GEMM2 -----------
__global__ __launch_bounds__(256, 1) void v2h_main(const float* __restrict__ adj,
                                                   const __bf16* __restrict__ nodeT,
                                                   const __bf16* __restrict__ Wb,
                                                   const float* __restrict__ bias,
                                                   float* __restrict__ out) {
    __shared__ __align__(16) __bf16 Bs[2][128][64];          // 32 KB, swizzled DMA layout
    __shared__ __align__(16) unsigned long long Abits[2][64];// 1 KB, dbuf bit tiles
    __shared__ __align__(16) float normS[BM];                // 256 B
    __shared__ __align__(16) __bf16 Ms[BM * MP];             // 17.4 KB

    const int t    = threadIdx.x;
    const int bid  = blockIdx.x;
    const int b    = bid & 7;            // batch -> XCD L2 locality for nodeT[b]
    const int e0   = (bid >> 3) * BM;    // bid>>3 in 0..31
    const int w    = t >> 6;             // wave id = f-group (32 cols)
    const int lane = t & 63;
    const int l15  = lane & 15;
    const int quad = lane >> 4;

    // adj-stream assignment: row arow = w*16 + (lane>>2), col-segment (lane&3)*16..+16
    const int ar   = lane >> 2;          // 0..15
    const int acs  = lane & 3;           // 0..3
    const int arow = w * 16 + ar;        // 0..63
    const float* aPtr = adj + ((size_t)b * E_ + e0 + arow) * N_ + acs * 16;

    const __bf16* nTB = nodeT + (size_t)b * F_ * N_;

    auto issue_dma = [&](int k0, int buf) {
#pragma unroll
        for (int p = 0; p < 4; ++p) {
            int idx = t + 256 * p;               // 0..1023
            int f   = idx >> 3;                  // 0..127
            int sl  = idx & 7;                   // LDS slot
            int g   = sl ^ (f & 7);              // global granule
            const __bf16* src = nTB + (size_t)f * N_ + k0 + g * 8;
            __bf16* dst = &Bs[buf][0][0] + (size_t)(w * 64 + 256 * p) * 8; // wave-uniform
            __builtin_amdgcn_global_load_lds(
                (const __attribute__((address_space(1))) void*)src,
                (__attribute__((address_space(3))) void*)dst, 16, 0, 0);
        }
    };

    auto cvt16 = [](float4 v0, float4 v1, float4 v2, float4 v3) -> unsigned {
        unsigned m = 0;
        m |= (v0.x == -1.f) ? 1u     : 0u;
        m |= (v0.y == -1.f) ? 2u     : 0u;
        m |= (v0.z == -1.f) ? 4u     : 0u;
        m |= (v0.w == -1.f) ? 8u     : 0u;
        m |= (v1.x == -1.f) ? 16u    : 0u;
        m |= (v1.y == -1.f) ? 32u    : 0u;
        m |= (v1.z == -1.f) ? 64u    : 0u;
        m |= (v1.w == -1.f) ? 128u   : 0u;
        m |= (v2.x == -1.f) ? 256u   : 0u;
        m |= (v2.y == -1.f) ? 512u   : 0u;
        m |= (v2.z == -1.f) ? 1024u  : 0u;
        m |= (v2.w == -1.f) ? 2048u  : 0u;
        m |= (v3.x == -1.f) ? 4096u  : 0u;
        m |= (v3.y == -1.f) ? 8192u  : 0u;
        m |= (v3.z == -1.f) ? 16384u : 0u;
        m |= (v3.w == -1.f) ? 32768u : 0u;
        return m;
    };

    auto unpack = [](unsigned byte) -> bf16x8 {
        union { unsigned u[4]; bf16x8 v; } r;
        r.u[0] = ((byte &   1u) ? 0x3F80u : 0u) | ((byte &   2u) ? 0x3F800000u : 0u);
        r.u[1] = ((byte &   4u) ? 0x3F80u : 0u) | ((byte &   8u) ? 0x3F800000u : 0u);
        r.u[2] = ((byte &  16u) ? 0x3F80u : 0u) | ((byte &  32u) ? 0x3F800000u : 0u);
        r.u[3] = ((byte &  64u) ? 0x3F80u : 0u) | ((byte & 128u) ? 0x3F800000u : 0u);
        return r.v;
    };

    fx4 acc[MT][2] = {};
    int cnt = 0;

    // ---- prologue: A(0) regs -> bits -> Abits[0]; B-DMA(0); A(1) regs in flight ----
    float4 a0 = *(const float4*)(aPtr + 0);
    float4 a1 = *(const float4*)(aPtr + 4);
    float4 a2 = *(const float4*)(aPtr + 8);
    float4 a3 = *(const float4*)(aPtr + 12);
    issue_dma(0, 0);
    {
        unsigned bits = cvt16(a0, a1, a2, a3);
        ((unsigned short*)&Abits[0][arow])[acs] = (unsigned short)bits;
        cnt += __popc(bits);
    }
    a0 = *(const float4*)(aPtr + BK + 0);
    a1 = *(const float4*)(aPtr + BK + 4);
    a2 = *(const float4*)(aPtr + BK + 8);
    a3 = *(const float4*)(aPtr + BK + 12);

#pragma unroll
    for (int m = 0; m < 32; ++m) {
        const int buf = m & 1;
        __syncthreads();   // drains B-DMA(m), adj regs; makes Abits[buf] visible

        if (m < 31)
            issue_dma((m + 1) * BK, buf ^ 1);
        if (m < 31) {
            unsigned bits = cvt16(a0, a1, a2, a3);   // A(m+1)
            ((unsigned short*)&Abits[buf ^ 1][arow])[acs] = (unsigned short)bits;
            cnt += __popc(bits);
        }
        if (m < 30) {
            const float* ap = aPtr + (m + 2) * BK;
            a0 = *(const float4*)(ap + 0);
            a1 = *(const float4*)(ap + 4);
            a2 = *(const float4*)(ap + 8);
            a3 = *(const float4*)(ap + 12);
        }

        // ---- A fragments from Abits[buf]: byte (ks*4+quad) of row-u64 ----
        bf16x8 af0[MT], af1[MT];
#pragma unroll
        for (int mt = 0; mt < MT; ++mt) {
            unsigned long long v = Abits[buf][mt * 16 + l15];
            unsigned lo = (unsigned)v, hi = (unsigned)(v >> 32);
            af0[mt] = unpack((lo >> (8 * quad)) & 255u);
            af1[mt] = unpack((hi >> (8 * quad)) & 255u);
        }

        // ---- B frag = row f, k-granule qg, at swizzled slot qg^(f&7); feeds 4 m-tiles
#pragma unroll
        for (int ft = 0; ft < 2; ++ft) {
            int f  = w * 32 + ft * 16 + l15;
            int q0 = quad ^ (f & 7);
            int q1 = (4 + quad) ^ (f & 7);
            bf16x8 b0 = *(const bf16x8*)&Bs[buf][f][q0 * 8];
#pragma unroll
            for (int mt = 0; mt < MT; ++mt)
                acc[mt][ft] = __builtin_amdgcn_mfma_f32_16x16x32_bf16(af0[mt], b0, acc[mt][ft], 0, 0, 0);
            bf16x8 b1 = *(const bf16x8*)&Bs[buf][f][q1 * 8];
#pragma unroll
            for (int mt = 0; mt < MT; ++mt)
                acc[mt][ft] = __builtin_amdgcn_mfma_f32_16x16x32_bf16(af1[mt], b1, acc[mt][ft], 0, 0, 0);
        }
    }

    // ---- norm: reduce count over the 4 col-segment threads of each row ----
    {
        float c = (float)cnt;
        c += __shfl_xor(c, 1);
        c += __shfl_xor(c, 2);
        if (acs == 0)
            normS[arow] = 1.f / fmaxf(c, 1.f);
    }
    __syncthreads();

    // ---- scale by 1/count, write msg bf16 to LDS in [m][f] layout ----
    const int rbase = quad * 4;
    float4 rn[MT];
#pragma unroll
    for (int mt = 0; mt < MT; ++mt)
        rn[mt] = *(const float4*)&normS[mt * 16 + rbase];

#pragma unroll
    for (int ft = 0; ft < 2; ++ft) {
        int fcol = w * 32 + ft * 16 + l15;
#pragma unroll
        for (int mt = 0; mt < MT; ++mt) {
            const float* rr = (const float*)&rn[mt];
#pragma unroll
            for (int r = 0; r < 4; ++r)
                Ms[(mt * 16 + rbase + r) * MP + fcol] = (__bf16)(acc[mt][ft][r] * rr[r]);
        }
    }
    __syncthreads();

    // ---- second GEMM: out[m][g] = sum_f msg[m][f] * W[g][f]; W direct from L2 ----
    fx4 acc2[MT][2] = {};
#pragma unroll
    for (int ks = 0; ks < 4; ++ks) {
        bf16x8 afm[MT];
#pragma unroll
        for (int mt = 0; mt < MT; ++mt)
            afm[mt] = *(const bf16x8*)&Ms[(mt * 16 + l15) * MP + ks * 32 + quad * 8];
#pragma unroll
        for (int gt = 0; gt < 2; ++gt) {
            int g = w * 32 + gt * 16 + l15;
            bf16x8 wfr = *(const bf16x8*)&Wb[(size_t)g * F_ + ks * 32 + quad * 8];
#pragma unroll
            for (int mt = 0; mt < MT; ++mt)
                acc2[mt][gt] = __builtin_amdgcn_mfma_f32_16x16x32_bf16(afm[mt], wfr, acc2[mt][gt], 0, 0, 0);
        }
    }

    // ---- bias + relu + store (all m-tiles) ----
#pragma unroll
    for (int gt = 0; gt < 2; ++gt) {
        int g = w * 32 + gt * 16 + l15;
        float bb = bias[g];
#pragma unroll
        for (int mt = 0; mt < MT; ++mt) {
#pragma unroll
            for (int r = 0; r < 4; ++r) {
                int e = e0 + mt * 16 + rbase + r;
                float v = acc2[mt][gt][r] + bb;
                out[((size_t)b * E_ + e) * F_ + g] = fmaxf(v, 0.f);
            }
        }
    }
}

extern "C" void kernel_launch(void* const* d_in, const int* in_sizes, int n_in,
                              void* d_out, int out_size, void* d_ws, size_t ws_size,
                              hipStream_t stream) {
    const float* node = (const float*)d_in[0];   // [B,N,F]
    const float* adj  = (const float*)d_in[1];   // [B,E,N]
    const float* W    = (const float*)d_in[2];   // [F,F]
    const float* bias = (const float*)d_in[3];   // [F]
    float* out = (float*)d_out;                  // [B,E,F]

    char* ws = (char*)d_ws;
    __bf16* nodeT = (__bf16*)ws;                        // 8 MB
    __bf16* Wb    = (__bf16*)(ws + 8 * 1024 * 1024);    // 32 KB

    prep_all<<<528, 256, 0, stream>>>(node, W, nodeT, Wb);
    v2h_main<<<256, 256, 0, stream>>>(adj, nodeT, Wb, bias, out);
}